// Round 18
// baseline (318.626 us; speedup 1.0000x reference)
//
#include <hip/hip_runtime.h>
#include <hip/hip_bf16.h>
#include <cstdint>
#include <cstddef>

#define VV 50000
#define HH 1024
#define NROWS 4096
#define VPAD 50432      // padded reordered-W rows (covers 20002+118*256)
#define SP1 4000
#define SP2 20000
#define SP3 50000

#define BM 256
#define BN 256
#define BK 128
#define NKT (HH / BK)           // 8
#define ROWB 144                // LDS row stride: 128 data + 16 pad
#define SLOT_B (BN * ROWB)      // 36864 B/slot (B only); dbuf 73728 -> 2 blocks/CU
#define NCH (SLOT_B / 16)       // 2304 chunks per tile
#define LPT 5                   // ceil(2304/512), i=4 guarded (wave-uniform)

// reordered-W column map: [0..3999]=weight, [4000..4001]=tail_vectors,
// [4002..50001]=weight[4000..49999], rest zero-pad
#define CB_T1 4002
#define CB_T2 20002
#define CL_HEAD 4002
#define CL_T1 20002
#define CL_T2 50002
#define CT_HEAD 16
#define CT_T1 63
#define CT_T2 118
#define PH_STRIDE 32    // 2*CT_HEAD
#define PT1_STRIDE 126  // 2*CT_T1
#define PT2_STRIDE 236  // 2*CT_T2
#define NRT 16          // row tiles (4096/256)
#define NB2 (NRT * CT_T2)       // 1888
#define NB1 (NRT * CT_T1)       // 1008
#define NBH (NRT * CT_HEAD)     // 256

// prep dispatch block ranges (256 threads each)
#define PB_CONVW 2048
#define PB_CONVH 128
#define PB_BIAS 197             // ceil(50432/256)
#define PB_TOTAL (PB_CONVW + PB_CONVH + PB_BIAS + 1)

#define WSCALE 256.0f
#define HSCALE 16.0f
#define INVSCALE (1.0f / 4096.0f)
#define UNIT_SCALE 0x7f7f7f7fu  // E8M0 1.0 in every byte

typedef __attribute__((ext_vector_type(4))) int i32x4;
typedef __attribute__((ext_vector_type(8))) int i32x8;
typedef __attribute__((ext_vector_type(4))) float f32x4;

typedef __attribute__((address_space(1))) unsigned int uint_g;
typedef __attribute__((address_space(3))) unsigned int uint_l;

__device__ __forceinline__ void gload16(const void* g, void* l) {
  __builtin_amdgcn_global_load_lds((const uint_g*)g, (uint_l*)l, 16, 0, 0);
}

// pack 4 floats -> 4 fp8 e4m3 bytes
__device__ __forceinline__ unsigned int pk4(float4 f, float s) {
  int p = __builtin_amdgcn_cvt_pk_fp8_f32(f.x * s, f.y * s, 0, 0);
  p = __builtin_amdgcn_cvt_pk_fp8_f32(f.z * s, f.w * s, p, 1);
  return (unsigned int)p;
}

// ---- fused prologue: convW | convH | biasK | scanK (all independent) ----
__global__ __launch_bounds__(256) void prep(
    const float* __restrict__ w, const float* __restrict__ tails,
    const float* __restrict__ bias, const float* __restrict__ tb,
    const float* __restrict__ h, const int* __restrict__ targets,
    unsigned char* __restrict__ Wf, unsigned char* __restrict__ Hf,
    float* __restrict__ biasr, int* __restrict__ cidx, int* __restrict__ counts,
    int* __restrict__ rixH, int* __restrict__ rix1, int* __restrict__ rix2) {
  const int b = blockIdx.x;
  const int tid = threadIdx.x;

  if (b < PB_CONVW) {
    // convW: fp8(x256), reordered rows; 16 elems/thread/iter, uint4 store
    const size_t n16 = (size_t)VPAD * HH / 16;
    for (size_t q = (size_t)b * 256 + tid; q < n16; q += (size_t)PB_CONVW * 256) {
      const size_t e = q * 16;
      const int row = (int)(e >> 10);
      uint4 o;
      if (row < 4000) {
        const float4* f = (const float4*)(w + e);
        o = make_uint4(pk4(f[0], WSCALE), pk4(f[1], WSCALE), pk4(f[2], WSCALE),
                       pk4(f[3], WSCALE));
      } else if (row < 4002) {
        const float4* f = (const float4*)(tails + (e - (size_t)4000 * HH));
        o = make_uint4(pk4(f[0], WSCALE), pk4(f[1], WSCALE), pk4(f[2], WSCALE),
                       pk4(f[3], WSCALE));
      } else if (row < 50002) {
        const float4* f = (const float4*)(w + (e - 2048));
        o = make_uint4(pk4(f[0], WSCALE), pk4(f[1], WSCALE), pk4(f[2], WSCALE),
                       pk4(f[3], WSCALE));
      } else {
        o = make_uint4(0u, 0u, 0u, 0u);
      }
      *(uint4*)(Wf + e) = o;
    }
  } else if (b < PB_CONVW + PB_CONVH) {
    // convH: fp8(x16); 16 elems/thread/iter
    const int bb = b - PB_CONVW;
    const size_t n16 = (size_t)NROWS * HH / 16;
    for (size_t q = (size_t)bb * 256 + tid; q < n16; q += (size_t)PB_CONVH * 256) {
      const size_t e = q * 16;
      const float4* f = (const float4*)(h + e);
      *(uint4*)(Hf + e) = make_uint4(pk4(f[0], HSCALE), pk4(f[1], HSCALE),
                                     pk4(f[2], HSCALE), pk4(f[3], HSCALE));
    }
  } else if (b < PB_CONVW + PB_CONVH + PB_BIAS) {
    // biasK: reordered bias (pads -1e30)
    const int r = (b - PB_CONVW - PB_CONVH) * 256 + tid;
    if (r < VPAD) {
      float v;
      if (r < 4000) v = bias[r];
      else if (r == 4000) v = tb[0];
      else if (r == 4001) v = tb[1];
      else if (r < 50002) v = bias[r - 2];
      else v = -1e30f;
      biasr[r] = v;
    }
  } else {
    // scanK: deterministic cluster scan; 256 threads x 16 rows
    __shared__ int s1[256], s2[256];
    for (int i = tid; i < NROWS; i += 256) {
      rix1[i] = 0;
      rix2[i] = 0;
    }
    __syncthreads();
    int c[16];
    int n1 = 0, n2 = 0;
#pragma unroll
    for (int j = 0; j < 16; j++) {
      const int t = targets[tid * 16 + j];
      c[j] = (t >= SP1) + (t >= SP2);
      n1 += (c[j] == 1);
      n2 += (c[j] == 2);
    }
    s1[tid] = n1;
    s2[tid] = n2;
    __syncthreads();
    for (int off = 1; off < 256; off <<= 1) {
      const int a1 = (tid >= off) ? s1[tid - off] : 0;
      const int a2 = (tid >= off) ? s2[tid - off] : 0;
      __syncthreads();
      s1[tid] += a1;
      s2[tid] += a2;
      __syncthreads();
    }
    int e1 = s1[tid] - n1, e2 = s2[tid] - n2;
#pragma unroll
    for (int j = 0; j < 16; j++) {
      const int row = tid * 16 + j;
      rixH[row] = row;
      if (c[j] == 1) {
        cidx[row] = e1;
        rix1[e1] = row;
        e1++;
      } else if (c[j] == 2) {
        cidx[row] = e2;
        rix2[e2] = row;
        e2++;
      } else {
        cidx[row] = 0;
      }
    }
    if (tid == 255) {
      counts[0] = s1[255];
      counts[1] = s2[255];
      counts[2] = NROWS;
    }
  }
}

// ---- fused MX-fp8 GEMM (all 3 segments) + sum-exp epilogue ----
// One dispatch, colTile fastest within each segment (trailing early-exits).
// 512 threads (8 waves = 4M x 2N, wave 64x128), BK=128.
// A-DIRECT: Hf is 4 MB (L2-resident) and consecutive blocks share the A
// tile, so A fragments load straight from global into regs (per row the 4
// fq-lanes cover a contiguous 128 B -> coalesced; NOT r11's B-direct, which
// streamed the 50 MB L3-tier Wf). B stays LDS-staged (gload_lds, padded
// rows, dup chunk). LDS = 2 x 36864 = 73728 -> 2 blocks/CU = 4 waves/SIMD.
// A-loads issue at iter top and drain inside the same counted vmcnt(4).
__global__ __launch_bounds__(512, 2) void gemm_fused(
    const unsigned char* __restrict__ Hf, const unsigned char* __restrict__ Wf,
    const float* __restrict__ biasr, float* __restrict__ ph,
    float* __restrict__ pt1, float* __restrict__ pt2,
    const int* __restrict__ counts, const int* __restrict__ rixH,
    const int* __restrict__ rix1, const int* __restrict__ rix2) {
  const int bid = blockIdx.x;
  const int* rix;
  float* partials;
  int CT, colbase, col_limit, b, Mc;
  if (bid < NB2) {
    b = bid; CT = CT_T2; colbase = CB_T2; col_limit = CL_T2;
    rix = rix2; partials = pt2; Mc = counts[1];
  } else if (bid < NB2 + NB1) {
    b = bid - NB2; CT = CT_T1; colbase = CB_T1; col_limit = CL_T1;
    rix = rix1; partials = pt1; Mc = counts[0];
  } else {
    b = bid - NB2 - NB1; CT = CT_HEAD; colbase = 0; col_limit = CL_HEAD;
    rix = rixH; partials = ph; Mc = NROWS;
  }
  const int rowTile = b / CT;
  const int colTile = b - rowTile * CT;
  if (rowTile * BM >= Mc) return;

  __shared__ __align__(16) unsigned char lds[2 * SLOT_B];  // 73728 B

  const int tid = threadIdx.x;
  const int w = tid >> 6, lane = tid & 63;
  const int wr = w >> 1, wc = w & 1;   // 4M x 2N
  const int fr = lane & 15, fq = lane >> 4;
  const unsigned char* Bg = Wf + (size_t)(colbase + colTile * BN) * HH;

  // A fragment base pointers (direct global): row rix[...], k base fq*32
  const unsigned char* aPtr[4];
#pragma unroll
  for (int mi = 0; mi < 4; mi++) {
    const int R = rowTile * BM + wr * 64 + mi * 16 + fr;
    aPtr[mi] = Hf + (size_t)rix[R] * HH + fq * 32;
  }

  // B staging: chunk c=i*512+tid (16B) -> dest byte c*16; 9 chunks/row
  // (j==8 dups j=0 into pad); i=4 valid only for tid<256 (wave-uniform).
  const unsigned char* srcPtr[LPT];
  bool valid[LPT];
#pragma unroll
  for (int i = 0; i < LPT; i++) {
    const int c = i * 512 + tid;
    valid[i] = (c < NCH);
    const int cs = valid[i] ? c : 0;
    const int row = cs / 9;
    const int j = cs - row * 9;
    const int jb = (j < 8) ? j * 16 : 0;
    srcPtr[i] = Bg + (size_t)row * HH + jb;
  }

  // B fragment read offsets (bytes within slot); hi half at +16
  int offB[8];
#pragma unroll
  for (int ni = 0; ni < 8; ni++) {
    const int R = wc * 128 + ni * 16 + fr;
    offB[ni] = R * ROWB + fq * 32;
  }

  f32x4 acc[4][8];
#pragma unroll
  for (int i = 0; i < 4; i++)
#pragma unroll
    for (int j = 0; j < 8; j++) acc[i][j] = (f32x4){0.f, 0.f, 0.f, 0.f};

  auto STAGE = [&](int t) {
    unsigned char* base = lds + (t & 1) * SLOT_B;
    const int k0 = t * BK;
#pragma unroll
    for (int i = 0; i < LPT; i++)
      if (valid[i]) gload16(srcPtr[i] + k0, base + (i * 512 + tid) * 16);
  };

  STAGE(0);

#pragma unroll 1
  for (int t = 0; t < NKT; ++t) {
    // A fragment loads for CURRENT tile (drained by the vmcnt below)
    i32x4 aLo[4], aHi[4];
    {
      const int k0 = t * BK;
#pragma unroll
      for (int mi = 0; mi < 4; mi++) {
        aLo[mi] = *(const i32x4*)(aPtr[mi] + k0);
        aHi[mi] = *(const i32x4*)(aPtr[mi] + k0 + 16);
      }
    }
    if (t + 1 < NKT) {
      STAGE(t + 1);
      asm volatile("s_waitcnt vmcnt(4)" ::: "memory");
    } else {
      asm volatile("s_waitcnt vmcnt(0)" ::: "memory");
    }
    __builtin_amdgcn_s_barrier();

    const unsigned char* sl = lds + (t & 1) * SLOT_B;
    // hold all 8 B fragments (64 VGPR)
    i32x8 b8[8];
#pragma unroll
    for (int ni = 0; ni < 8; ni++) {
      i32x4 lo = *(const i32x4*)(sl + offB[ni]);
      i32x4 hi = *(const i32x4*)(sl + offB[ni] + 16);
      b8[ni] = __builtin_shufflevector(lo, hi, 0, 1, 2, 3, 4, 5, 6, 7);
    }
    __builtin_amdgcn_s_setprio(1);
#pragma unroll
    for (int mi = 0; mi < 4; mi++) {
      i32x8 a8 = __builtin_shufflevector(aLo[mi], aHi[mi], 0, 1, 2, 3, 4, 5, 6, 7);
#pragma unroll
      for (int ni = 0; ni < 8; ni++)
        acc[mi][ni] = __builtin_amdgcn_mfma_scale_f32_16x16x128_f8f6f4(
            a8, b8[ni], acc[mi][ni], 0, 0, 0, UNIT_SCALE, 0, UNIT_SCALE);
    }
    __builtin_amdgcn_s_setprio(0);
    __builtin_amdgcn_s_barrier();
  }

  // ---- epilogue: per-(row, 128-col wave chunk) sum of exp(logit/4096+bias) ----
  const int colw = colTile * BN + wc * 128;
  float biasv[8];
#pragma unroll
  for (int ni = 0; ni < 8; ni++) {
    const int gcol = colbase + colw + ni * 16 + fr;
    biasv[ni] = (gcol < col_limit) ? biasr[gcol] : -1e30f;
  }
  const int chunk = colTile * 2 + wc;
  const int pstride = CT * 2;

#pragma unroll
  for (int mi = 0; mi < 4; mi++) {
    const int rowg = rowTile * BM + wr * 64 + mi * 16 + fq * 4;
#pragma unroll
    for (int r = 0; r < 4; r++) {
      float p = 0.f;
#pragma unroll
      for (int ni = 0; ni < 8; ni++)
        p += __expf(acc[mi][ni][r] * INVSCALE + biasv[ni]);
#pragma unroll
      for (int m = 1; m < 16; m <<= 1) p += __shfl_xor(p, m);
      if (fr == 0) partials[(size_t)(rowg + r) * pstride + chunk] = p;
    }
  }
}

// ---- per-row: combine chunk partials, selected logits in fp32, loss ----
__global__ __launch_bounds__(256) void rowloss(
    const float* __restrict__ ph, const float* __restrict__ pt1,
    const float* __restrict__ pt2, const int* __restrict__ cidx,
    const float* __restrict__ hiddens, const float* __restrict__ weight,
    const float* __restrict__ bias, const float* __restrict__ tails,
    const float* __restrict__ tail_bias, const int* __restrict__ targets,
    float* __restrict__ losses) {
  const int row = blockIdx.x * 4 + (threadIdx.x >> 6);
  const int lane = threadIdx.x & 63;
  const int t = targets[row];
  const int cl = (t >= SP1) + (t >= SP2);

  float s0 = (lane < PH_STRIDE) ? ph[(size_t)row * PH_STRIDE + lane] : 0.f;
  float st = 0.f;
  if (cl == 1) {
    const float* P = pt1 + (size_t)cidx[row] * PT1_STRIDE;
    for (int c = lane; c < PT1_STRIDE; c += 64) st += P[c];
  } else if (cl == 2) {
    const float* P = pt2 + (size_t)cidx[row] * PT2_STRIDE;
    for (int c = lane; c < PT2_STRIDE; c += 64) st += P[c];
  }
#pragma unroll
  for (int m = 1; m < 64; m <<= 1) {
    s0 += __shfl_xor(s0, m);
    st += __shfl_xor(st, m);
  }

  const float* hv = hiddens + (size_t)row * HH;
  const float* w1;
  float b1;
  if (cl == 0) {
    w1 = weight + (size_t)t * HH;
    b1 = bias[t];
  } else if (cl == 1) {
    w1 = tails + HH;  // head col 4001 <-> tail_vectors[1]
    b1 = tail_bias[1];
  } else {
    w1 = tails;       // head col 4000 <-> tail_vectors[0]
    b1 = tail_bias[0];
  }
  float d1 = 0.f, d2 = 0.f;
  for (int i = lane; i < HH; i += 64) d1 += hv[i] * w1[i];
  if (cl > 0) {
    const float* w2 = weight + (size_t)t * HH;
    for (int i = lane; i < HH; i += 64) d2 += hv[i] * w2[i];
  }
#pragma unroll
  for (int m = 1; m < 64; m <<= 1) {
    d1 += __shfl_xor(d1, m);
    d2 += __shfl_xor(d2, m);
  }
  if (lane == 0) {
    float loss = logf(s0) - (d1 + b1);
    if (cl > 0) loss += logf(st) - (d2 + bias[t]);
    losses[row] = loss;
  }
}

__global__ void meanloss(const float* __restrict__ losses, float* __restrict__ out) {
  __shared__ float red[256];
  float s = 0.f;
  for (int i = threadIdx.x; i < NROWS; i += 256) s += losses[i];
  red[threadIdx.x] = s;
  __syncthreads();
  for (int st = 128; st > 0; st >>= 1) {
    if ((int)threadIdx.x < st) red[threadIdx.x] += red[threadIdx.x + st];
    __syncthreads();
  }
  if (threadIdx.x == 0) out[0] = red[0] / (float)NROWS;
}

extern "C" void kernel_launch(void* const* d_in, const int* in_sizes, int n_in,
                              void* d_out, int out_size, void* d_ws, size_t ws_size,
                              hipStream_t stream) {
  const float* weight = (const float*)d_in[0];
  const float* bias = (const float*)d_in[1];
  const float* hiddens = (const float*)d_in[2];
  const float* tails = (const float*)d_in[3];
  const float* tail_bias = (const float*)d_in[4];
  const int* targets = (const int*)d_in[5];
  float* out = (float*)d_out;

  char* ws = (char*)d_ws;
  unsigned char* Wf = (unsigned char*)ws;                      // 50432*1024 = 51,642,368
  unsigned char* Hf = (unsigned char*)(ws + 51642368);         //  4,194,304
  float* ph = (float*)(ws + 55836672);                         //  4096*32*4  =   524,288
  float* pt1 = (float*)(ws + 56360960);                        //  4096*126*4 = 2,064,384
  float* pt2 = (float*)(ws + 58425344);                        //  4096*236*4 = 3,866,624
  float* biasr = (float*)(ws + 62291968);                      //  50432*4    =   201,728
  int* cidx = (int*)(ws + 62493696);                           //  16,384
  int* counts = (int*)(ws + 62510080);                         //  64
  int* rixH = (int*)(ws + 62510144);                           //  16,384
  int* rix1 = (int*)(ws + 62526528);                           //  16,384
  int* rix2 = (int*)(ws + 62542912);                           //  16,384
  float* losses = (float*)(ws + 62559296);                     //  16,384

  hipLaunchKernelGGL(prep, dim3(PB_TOTAL), dim3(256), 0, stream, weight, tails, bias,
                     tail_bias, hiddens, targets, Wf, Hf, biasr, cidx, counts, rixH,
                     rix1, rix2);
  // fused: tail2 blocks [0,1888), tail1 [1888,2896), head [2896,3152)
  hipLaunchKernelGGL(gemm_fused, dim3(NB2 + NB1 + NBH), dim3(512), 0, stream, Hf, Wf,
                     biasr, ph, pt1, pt2, counts, rixH, rix1, rix2);
  hipLaunchKernelGGL(rowloss, dim3(NROWS / 4), dim3(256), 0, stream, ph, pt1, pt2, cidx,
                     hiddens, weight, bias, tails, tail_bias, targets, losses);
  hipLaunchKernelGGL(meanloss, dim3(1), dim3(256), 0, stream, losses, out);
}

// Round 19
// 242.279 us; speedup vs baseline: 1.3151x; 1.3151x over previous
//
#include <hip/hip_runtime.h>
#include <hip/hip_bf16.h>
#include <cstdint>
#include <cstddef>

#define VV 50000
#define HH 1024
#define NROWS 4096
#define VPAD 50432      // padded reordered-W rows (covers 20002+118*256)
#define SP1 4000
#define SP2 20000
#define SP3 50000

#define BM 256
#define BN 256
#define BK 128
#define NKT (HH / BK)           // 8
#define ROWB 144                // LDS row stride: 128 data + 16 pad
#define A_SLOT_B (BM * ROWB)    // 36864
#define SLOT_B (2 * A_SLOT_B)   // 73728 B/slot; dbuf 147456 -> 1 block/CU
#define NCH (SLOT_B / 16)       // 4608 chunks per tile
#define LPT (NCH / 512)         // 9 loads per thread per tile

// reordered-W column map: [0..3999]=weight, [4000..4001]=tail_vectors,
// [4002..50001]=weight[4000..49999], rest zero-pad
#define CB_T1 4002
#define CB_T2 20002
#define CL_HEAD 4002
#define CL_T1 20002
#define CL_T2 50002
#define CT_HEAD 16
#define CT_T1 63
#define CT_T2 118
#define PH_STRIDE 32    // 2*CT_HEAD
#define PT1_STRIDE 126  // 2*CT_T1
#define PT2_STRIDE 236  // 2*CT_T2
#define NRT 16          // row tiles (4096/256)
#define NB2 (NRT * CT_T2)       // 1888
#define NB1 (NRT * CT_T1)       // 1008
#define NBH (NRT * CT_HEAD)     // 256

// prep dispatch block ranges (256 threads each)
#define PB_CONVW 2048
#define PB_CONVH 128
#define PB_BIAS 197             // ceil(50432/256)
#define PB_TOTAL (PB_CONVW + PB_CONVH + PB_BIAS + 1)

#define WSCALE 256.0f
#define HSCALE 16.0f
#define INVSCALE (1.0f / 4096.0f)
#define UNIT_SCALE 0x7f7f7f7fu  // E8M0 1.0 in every byte

typedef __attribute__((ext_vector_type(4))) int i32x4;
typedef __attribute__((ext_vector_type(8))) int i32x8;
typedef __attribute__((ext_vector_type(4))) float f32x4;

typedef __attribute__((address_space(1))) unsigned int uint_g;
typedef __attribute__((address_space(3))) unsigned int uint_l;

__device__ __forceinline__ void gload16(const void* g, void* l) {
  __builtin_amdgcn_global_load_lds((const uint_g*)g, (uint_l*)l, 16, 0, 0);
}

// pack 4 floats -> 4 fp8 e4m3 bytes
__device__ __forceinline__ unsigned int pk4(float4 f, float s) {
  int p = __builtin_amdgcn_cvt_pk_fp8_f32(f.x * s, f.y * s, 0, 0);
  p = __builtin_amdgcn_cvt_pk_fp8_f32(f.z * s, f.w * s, p, 1);
  return (unsigned int)p;
}

// ---- fused prologue: convW | convH | biasK | scanK (all independent) ----
__global__ __launch_bounds__(256) void prep(
    const float* __restrict__ w, const float* __restrict__ tails,
    const float* __restrict__ bias, const float* __restrict__ tb,
    const float* __restrict__ h, const int* __restrict__ targets,
    unsigned char* __restrict__ Wf, unsigned char* __restrict__ Hf,
    float* __restrict__ biasr, int* __restrict__ cidx, int* __restrict__ counts,
    int* __restrict__ rixH, int* __restrict__ rix1, int* __restrict__ rix2) {
  const int b = blockIdx.x;
  const int tid = threadIdx.x;

  if (b < PB_CONVW) {
    // convW: fp8(x256), reordered rows; 16 elems/thread/iter, uint4 store
    const size_t n16 = (size_t)VPAD * HH / 16;
    for (size_t q = (size_t)b * 256 + tid; q < n16; q += (size_t)PB_CONVW * 256) {
      const size_t e = q * 16;
      const int row = (int)(e >> 10);
      uint4 o;
      if (row < 4000) {
        const float4* f = (const float4*)(w + e);
        o = make_uint4(pk4(f[0], WSCALE), pk4(f[1], WSCALE), pk4(f[2], WSCALE),
                       pk4(f[3], WSCALE));
      } else if (row < 4002) {
        const float4* f = (const float4*)(tails + (e - (size_t)4000 * HH));
        o = make_uint4(pk4(f[0], WSCALE), pk4(f[1], WSCALE), pk4(f[2], WSCALE),
                       pk4(f[3], WSCALE));
      } else if (row < 50002) {
        const float4* f = (const float4*)(w + (e - 2048));
        o = make_uint4(pk4(f[0], WSCALE), pk4(f[1], WSCALE), pk4(f[2], WSCALE),
                       pk4(f[3], WSCALE));
      } else {
        o = make_uint4(0u, 0u, 0u, 0u);
      }
      *(uint4*)(Wf + e) = o;
    }
  } else if (b < PB_CONVW + PB_CONVH) {
    // convH: fp8(x16); 16 elems/thread/iter
    const int bb = b - PB_CONVW;
    const size_t n16 = (size_t)NROWS * HH / 16;
    for (size_t q = (size_t)bb * 256 + tid; q < n16; q += (size_t)PB_CONVH * 256) {
      const size_t e = q * 16;
      const float4* f = (const float4*)(h + e);
      *(uint4*)(Hf + e) = make_uint4(pk4(f[0], HSCALE), pk4(f[1], HSCALE),
                                     pk4(f[2], HSCALE), pk4(f[3], HSCALE));
    }
  } else if (b < PB_CONVW + PB_CONVH + PB_BIAS) {
    // biasK: reordered bias (pads -1e30)
    const int r = (b - PB_CONVW - PB_CONVH) * 256 + tid;
    if (r < VPAD) {
      float v;
      if (r < 4000) v = bias[r];
      else if (r == 4000) v = tb[0];
      else if (r == 4001) v = tb[1];
      else if (r < 50002) v = bias[r - 2];
      else v = -1e30f;
      biasr[r] = v;
    }
  } else {
    // scanK: deterministic cluster scan; 256 threads x 16 rows
    __shared__ int s1[256], s2[256];
    for (int i = tid; i < NROWS; i += 256) {
      rix1[i] = 0;
      rix2[i] = 0;
    }
    __syncthreads();
    int c[16];
    int n1 = 0, n2 = 0;
#pragma unroll
    for (int j = 0; j < 16; j++) {
      const int t = targets[tid * 16 + j];
      c[j] = (t >= SP1) + (t >= SP2);
      n1 += (c[j] == 1);
      n2 += (c[j] == 2);
    }
    s1[tid] = n1;
    s2[tid] = n2;
    __syncthreads();
    for (int off = 1; off < 256; off <<= 1) {
      const int a1 = (tid >= off) ? s1[tid - off] : 0;
      const int a2 = (tid >= off) ? s2[tid - off] : 0;
      __syncthreads();
      s1[tid] += a1;
      s2[tid] += a2;
      __syncthreads();
    }
    int e1 = s1[tid] - n1, e2 = s2[tid] - n2;
#pragma unroll
    for (int j = 0; j < 16; j++) {
      const int row = tid * 16 + j;
      rixH[row] = row;
      if (c[j] == 1) {
        cidx[row] = e1;
        rix1[e1] = row;
        e1++;
      } else if (c[j] == 2) {
        cidx[row] = e2;
        rix2[e2] = row;
        e2++;
      } else {
        cidx[row] = 0;
      }
    }
    if (tid == 255) {
      counts[0] = s1[255];
      counts[1] = s2[255];
      counts[2] = NROWS;
    }
  }
}

// ---- fused MX-fp8 GEMM (all 3 segments) + sum-exp epilogue ----
// r13/r17 proven body (182 us, MfmaUtil 28, VGPR 116, no spill): 512 threads
// (8 waves = 4M x 2N, wave 64x128 -> 0.75 KB LDS-read/MFMA), BK=128, A+B
// LDS-staged (gload_lds, 144-B padded rows, dup chunk), dbuf 147456 B,
// vmcnt(9), unroll 1. A rows staged via rix[] indirection straight from Hf
// (per-lane global src is legal for gload_lds) -> no gather/zero kernels.
__global__ __launch_bounds__(512, 2) void gemm_fused(
    const unsigned char* __restrict__ Hf, const unsigned char* __restrict__ Wf,
    const float* __restrict__ biasr, float* __restrict__ ph,
    float* __restrict__ pt1, float* __restrict__ pt2,
    const int* __restrict__ counts, const int* __restrict__ rixH,
    const int* __restrict__ rix1, const int* __restrict__ rix2) {
  const int bid = blockIdx.x;
  const int* rix;
  float* partials;
  int CT, colbase, col_limit, b, Mc;
  if (bid < NB2) {
    b = bid; CT = CT_T2; colbase = CB_T2; col_limit = CL_T2;
    rix = rix2; partials = pt2; Mc = counts[1];
  } else if (bid < NB2 + NB1) {
    b = bid - NB2; CT = CT_T1; colbase = CB_T1; col_limit = CL_T1;
    rix = rix1; partials = pt1; Mc = counts[0];
  } else {
    b = bid - NB2 - NB1; CT = CT_HEAD; colbase = 0; col_limit = CL_HEAD;
    rix = rixH; partials = ph; Mc = NROWS;
  }
  const int rowTile = b / CT;
  const int colTile = b - rowTile * CT;
  if (rowTile * BM >= Mc) return;

  __shared__ __align__(16) unsigned char lds[2 * SLOT_B];  // 147456 B

  const int tid = threadIdx.x;
  const int w = tid >> 6, lane = tid & 63;
  const int wr = w >> 1, wc = w & 1;   // 4M x 2N
  const int fr = lane & 15, fq = lane >> 4;
  const unsigned char* Bg = Wf + (size_t)(colbase + colTile * BN) * HH;

  // staging: chunk c=i*512+tid (16B) -> dest byte c*16.
  // rows 0..255 = A (indirect via rix), 256..511 = B; 9 chunks/row
  // (j==8 dups j=0 into pad). A/B boundary at c=2304.
  const unsigned char* srcPtr[LPT];
#pragma unroll
  for (int i = 0; i < LPT; i++) {
    const int c = i * 512 + tid;
    const bool isA = c < NCH / 2;
    const int cc = isA ? c : c - NCH / 2;
    const int row = cc / 9;
    const int j = cc - row * 9;
    const int jb = (j < 8) ? j * 16 : 0;
    if (isA)
      srcPtr[i] = Hf + (size_t)rix[rowTile * BM + row] * HH + jb;
    else
      srcPtr[i] = Bg + (size_t)row * HH + jb;
  }

  // fragment read offsets (bytes within slot); hi half at +16 (contiguous)
  int offA[4], offB[8];
#pragma unroll
  for (int mi = 0; mi < 4; mi++) {
    const int R = wr * 64 + mi * 16 + fr;
    offA[mi] = R * ROWB + fq * 32;
  }
#pragma unroll
  for (int ni = 0; ni < 8; ni++) {
    const int R = wc * 128 + ni * 16 + fr;
    offB[ni] = A_SLOT_B + R * ROWB + fq * 32;
  }

  f32x4 acc[4][8];
#pragma unroll
  for (int i = 0; i < 4; i++)
#pragma unroll
    for (int j = 0; j < 8; j++) acc[i][j] = (f32x4){0.f, 0.f, 0.f, 0.f};

  auto STAGE = [&](int t) {
    unsigned char* base = lds + (t & 1) * SLOT_B;
    const int k0 = t * BK;
#pragma unroll
    for (int i = 0; i < LPT; i++)
      gload16(srcPtr[i] + k0, base + (i * 512 + tid) * 16);
  };

  STAGE(0);

#pragma unroll 1
  for (int t = 0; t < NKT; ++t) {
    if (t + 1 < NKT) {
      STAGE(t + 1);
      asm volatile("s_waitcnt vmcnt(9)" ::: "memory");
    } else {
      asm volatile("s_waitcnt vmcnt(0)" ::: "memory");
    }
    __builtin_amdgcn_s_barrier();

    const unsigned char* sl = lds + (t & 1) * SLOT_B;
    // hold all 8 B fragments (64 VGPR)
    i32x8 b8[8];
#pragma unroll
    for (int ni = 0; ni < 8; ni++) {
      i32x4 lo = *(const i32x4*)(sl + offB[ni]);
      i32x4 hi = *(const i32x4*)(sl + offB[ni] + 16);
      b8[ni] = __builtin_shufflevector(lo, hi, 0, 1, 2, 3, 4, 5, 6, 7);
    }
    __builtin_amdgcn_s_setprio(1);
#pragma unroll
    for (int mi = 0; mi < 4; mi++) {
      i32x4 lo = *(const i32x4*)(sl + offA[mi]);
      i32x4 hi = *(const i32x4*)(sl + offA[mi] + 16);
      i32x8 a8 = __builtin_shufflevector(lo, hi, 0, 1, 2, 3, 4, 5, 6, 7);
#pragma unroll
      for (int ni = 0; ni < 8; ni++)
        acc[mi][ni] = __builtin_amdgcn_mfma_scale_f32_16x16x128_f8f6f4(
            a8, b8[ni], acc[mi][ni], 0, 0, 0, UNIT_SCALE, 0, UNIT_SCALE);
    }
    __builtin_amdgcn_s_setprio(0);
    __builtin_amdgcn_s_barrier();
  }

  // ---- epilogue: per-(row, 128-col wave chunk) sum of exp(logit/4096+bias) ----
  const int colw = colTile * BN + wc * 128;
  float biasv[8];
#pragma unroll
  for (int ni = 0; ni < 8; ni++) {
    const int gcol = colbase + colw + ni * 16 + fr;
    biasv[ni] = (gcol < col_limit) ? biasr[gcol] : -1e30f;
  }
  const int chunk = colTile * 2 + wc;
  const int pstride = CT * 2;

#pragma unroll
  for (int mi = 0; mi < 4; mi++) {
    const int rowg = rowTile * BM + wr * 64 + mi * 16 + fq * 4;
#pragma unroll
    for (int r = 0; r < 4; r++) {
      float p = 0.f;
#pragma unroll
      for (int ni = 0; ni < 8; ni++)
        p += __expf(acc[mi][ni][r] * INVSCALE + biasv[ni]);
#pragma unroll
      for (int m = 1; m < 16; m <<= 1) p += __shfl_xor(p, m);
      if (fr == 0) partials[(size_t)(rowg + r) * pstride + chunk] = p;
    }
  }
}

// ---- per-row: combine chunk partials, selected logits in fp32, loss ----
__global__ __launch_bounds__(256) void rowloss(
    const float* __restrict__ ph, const float* __restrict__ pt1,
    const float* __restrict__ pt2, const int* __restrict__ cidx,
    const float* __restrict__ hiddens, const float* __restrict__ weight,
    const float* __restrict__ bias, const float* __restrict__ tails,
    const float* __restrict__ tail_bias, const int* __restrict__ targets,
    float* __restrict__ losses) {
  const int row = blockIdx.x * 4 + (threadIdx.x >> 6);
  const int lane = threadIdx.x & 63;
  const int t = targets[row];
  const int cl = (t >= SP1) + (t >= SP2);

  float s0 = (lane < PH_STRIDE) ? ph[(size_t)row * PH_STRIDE + lane] : 0.f;
  float st = 0.f;
  if (cl == 1) {
    const float* P = pt1 + (size_t)cidx[row] * PT1_STRIDE;
    for (int c = lane; c < PT1_STRIDE; c += 64) st += P[c];
  } else if (cl == 2) {
    const float* P = pt2 + (size_t)cidx[row] * PT2_STRIDE;
    for (int c = lane; c < PT2_STRIDE; c += 64) st += P[c];
  }
#pragma unroll
  for (int m = 1; m < 64; m <<= 1) {
    s0 += __shfl_xor(s0, m);
    st += __shfl_xor(st, m);
  }

  const float* hv = hiddens + (size_t)row * HH;
  const float* w1;
  float b1;
  if (cl == 0) {
    w1 = weight + (size_t)t * HH;
    b1 = bias[t];
  } else if (cl == 1) {
    w1 = tails + HH;  // head col 4001 <-> tail_vectors[1]
    b1 = tail_bias[1];
  } else {
    w1 = tails;       // head col 4000 <-> tail_vectors[0]
    b1 = tail_bias[0];
  }
  float d1 = 0.f, d2 = 0.f;
  for (int i = lane; i < HH; i += 64) d1 += hv[i] * w1[i];
  if (cl > 0) {
    const float* w2 = weight + (size_t)t * HH;
    for (int i = lane; i < HH; i += 64) d2 += hv[i] * w2[i];
  }
#pragma unroll
  for (int m = 1; m < 64; m <<= 1) {
    d1 += __shfl_xor(d1, m);
    d2 += __shfl_xor(d2, m);
  }
  if (lane == 0) {
    float loss = logf(s0) - (d1 + b1);
    if (cl > 0) loss += logf(st) - (d2 + bias[t]);
    losses[row] = loss;
  }
}

__global__ void meanloss(const float* __restrict__ losses, float* __restrict__ out) {
  __shared__ float red[256];
  float s = 0.f;
  for (int i = threadIdx.x; i < NROWS; i += 256) s += losses[i];
  red[threadIdx.x] = s;
  __syncthreads();
  for (int st = 128; st > 0; st >>= 1) {
    if ((int)threadIdx.x < st) red[threadIdx.x] += red[threadIdx.x + st];
    __syncthreads();
  }
  if (threadIdx.x == 0) out[0] = red[0] / (float)NROWS;
}

extern "C" void kernel_launch(void* const* d_in, const int* in_sizes, int n_in,
                              void* d_out, int out_size, void* d_ws, size_t ws_size,
                              hipStream_t stream) {
  const float* weight = (const float*)d_in[0];
  const float* bias = (const float*)d_in[1];
  const float* hiddens = (const float*)d_in[2];
  const float* tails = (const float*)d_in[3];
  const float* tail_bias = (const float*)d_in[4];
  const int* targets = (const int*)d_in[5];
  float* out = (float*)d_out;

  char* ws = (char*)d_ws;
  unsigned char* Wf = (unsigned char*)ws;                      // 50432*1024 = 51,642,368
  unsigned char* Hf = (unsigned char*)(ws + 51642368);         //  4,194,304
  float* ph = (float*)(ws + 55836672);                         //  4096*32*4  =   524,288
  float* pt1 = (float*)(ws + 56360960);                        //  4096*126*4 = 2,064,384
  float* pt2 = (float*)(ws + 58425344);                        //  4096*236*4 = 3,866,624
  float* biasr = (float*)(ws + 62291968);                      //  50432*4    =   201,728
  int* cidx = (int*)(ws + 62493696);                           //  16,384
  int* counts = (int*)(ws + 62510080);                         //  64
  int* rixH = (int*)(ws + 62510144);                           //  16,384
  int* rix1 = (int*)(ws + 62526528);                           //  16,384
  int* rix2 = (int*)(ws + 62542912);                           //  16,384
  float* losses = (float*)(ws + 62559296);                     //  16,384

  hipLaunchKernelGGL(prep, dim3(PB_TOTAL), dim3(256), 0, stream, weight, tails, bias,
                     tail_bias, hiddens, targets, Wf, Hf, biasr, cidx, counts, rixH,
                     rix1, rix2);
  // fused: tail2 blocks [0,1888), tail1 [1888,2896), head [2896,3152)
  hipLaunchKernelGGL(gemm_fused, dim3(NB2 + NB1 + NBH), dim3(512), 0, stream, Hf, Wf,
                     biasr, ph, pt1, pt2, counts, rixH, rix1, rix2);
  hipLaunchKernelGGL(rowloss, dim3(NROWS / 4), dim3(256), 0, stream, ph, pt1, pt2, cidx,
                     hiddens, weight, bias, tails, tail_bias, targets, losses);
  hipLaunchKernelGGL(meanloss, dim3(1), dim3(256), 0, stream, losses, out);
}

// Round 20
// 239.819 us; speedup vs baseline: 1.3286x; 1.0103x over previous
//
#include <hip/hip_runtime.h>
#include <hip/hip_bf16.h>
#include <cstdint>
#include <cstddef>

#define VV 50000
#define HH 1024
#define NROWS 4096
#define VPAD 50432      // padded reordered-W rows (covers 20002+118*256)
#define SP1 4000
#define SP2 20000
#define SP3 50000

#define BM 256
#define BN 256
#define BK 128
#define NKT (HH / BK)           // 8
#define ROWB 144                // LDS row stride: 128 data + 16 pad
#define A_SLOT_B (BM * ROWB)    // 36864
#define SLOT_B (2 * A_SLOT_B)   // 73728 B/slot; dbuf 147456 -> 1 block/CU
#define NCH (SLOT_B / 16)       // 4608 chunks per tile
#define LPT (NCH / 512)         // 9 loads per thread per tile

// reordered-W column map: [0..3999]=weight, [4000..4001]=tail_vectors,
// [4002..50001]=weight[4000..49999], rest zero-pad
#define CB_T1 4002
#define CB_T2 20002
#define CL_HEAD 4002
#define CL_T1 20002
#define CL_T2 50002
#define CT_HEAD 16
#define CT_T1 63
#define CT_T2 118
#define PH_STRIDE 32    // 2*CT_HEAD
#define PT1_STRIDE 126  // 2*CT_T1
#define PT2_STRIDE 236  // 2*CT_T2
#define NRT 16          // row tiles (4096/256)
#define NB2 (NRT * CT_T2)       // 1888
#define NB1 (NRT * CT_T1)       // 1008
#define NBH (NRT * CT_HEAD)     // 256

// prep dispatch block ranges (256 threads each)
#define PB_CONVW 2048
#define PB_CONVH 128
#define PB_BIAS 197             // ceil(50432/256)
#define PB_TOTAL (PB_CONVW + PB_CONVH + PB_BIAS + 1)

#define WSCALE 256.0f
#define HSCALE 16.0f
#define INVSCALE (1.0f / 4096.0f)
#define UNIT_SCALE 0x7f7f7f7fu  // E8M0 1.0 in every byte

typedef __attribute__((ext_vector_type(4))) int i32x4;
typedef __attribute__((ext_vector_type(8))) int i32x8;
typedef __attribute__((ext_vector_type(4))) float f32x4;

typedef __attribute__((address_space(1))) unsigned int uint_g;
typedef __attribute__((address_space(3))) unsigned int uint_l;

__device__ __forceinline__ void gload16(const void* g, void* l) {
  __builtin_amdgcn_global_load_lds((const uint_g*)g, (uint_l*)l, 16, 0, 0);
}

// pack 4 floats -> 4 fp8 e4m3 bytes
__device__ __forceinline__ unsigned int pk4(float4 f, float s) {
  int p = __builtin_amdgcn_cvt_pk_fp8_f32(f.x * s, f.y * s, 0, 0);
  p = __builtin_amdgcn_cvt_pk_fp8_f32(f.z * s, f.w * s, p, 1);
  return (unsigned int)p;
}

// ---- fused prologue: convW | convH | biasK | scanK (all independent) ----
__global__ __launch_bounds__(256) void prep(
    const float* __restrict__ w, const float* __restrict__ tails,
    const float* __restrict__ bias, const float* __restrict__ tb,
    const float* __restrict__ h, const int* __restrict__ targets,
    unsigned char* __restrict__ Wf, unsigned char* __restrict__ Hf,
    float* __restrict__ biasr, int* __restrict__ cidx, int* __restrict__ counts,
    int* __restrict__ rixH, int* __restrict__ rix1, int* __restrict__ rix2) {
  const int b = blockIdx.x;
  const int tid = threadIdx.x;

  if (b < PB_CONVW) {
    // convW: fp8(x256), reordered rows; 16 elems/thread/iter, uint4 store
    const size_t n16 = (size_t)VPAD * HH / 16;
    for (size_t q = (size_t)b * 256 + tid; q < n16; q += (size_t)PB_CONVW * 256) {
      const size_t e = q * 16;
      const int row = (int)(e >> 10);
      uint4 o;
      if (row < 4000) {
        const float4* f = (const float4*)(w + e);
        o = make_uint4(pk4(f[0], WSCALE), pk4(f[1], WSCALE), pk4(f[2], WSCALE),
                       pk4(f[3], WSCALE));
      } else if (row < 4002) {
        const float4* f = (const float4*)(tails + (e - (size_t)4000 * HH));
        o = make_uint4(pk4(f[0], WSCALE), pk4(f[1], WSCALE), pk4(f[2], WSCALE),
                       pk4(f[3], WSCALE));
      } else if (row < 50002) {
        const float4* f = (const float4*)(w + (e - 2048));
        o = make_uint4(pk4(f[0], WSCALE), pk4(f[1], WSCALE), pk4(f[2], WSCALE),
                       pk4(f[3], WSCALE));
      } else {
        o = make_uint4(0u, 0u, 0u, 0u);
      }
      *(uint4*)(Wf + e) = o;
    }
  } else if (b < PB_CONVW + PB_CONVH) {
    // convH: fp8(x16); 16 elems/thread/iter
    const int bb = b - PB_CONVW;
    const size_t n16 = (size_t)NROWS * HH / 16;
    for (size_t q = (size_t)bb * 256 + tid; q < n16; q += (size_t)PB_CONVH * 256) {
      const size_t e = q * 16;
      const float4* f = (const float4*)(h + e);
      *(uint4*)(Hf + e) = make_uint4(pk4(f[0], HSCALE), pk4(f[1], HSCALE),
                                     pk4(f[2], HSCALE), pk4(f[3], HSCALE));
    }
  } else if (b < PB_CONVW + PB_CONVH + PB_BIAS) {
    // biasK: reordered bias (pads -1e30)
    const int r = (b - PB_CONVW - PB_CONVH) * 256 + tid;
    if (r < VPAD) {
      float v;
      if (r < 4000) v = bias[r];
      else if (r == 4000) v = tb[0];
      else if (r == 4001) v = tb[1];
      else if (r < 50002) v = bias[r - 2];
      else v = -1e30f;
      biasr[r] = v;
    }
  } else {
    // scanK: deterministic cluster scan; 256 threads x 16 rows
    __shared__ int s1[256], s2[256];
    for (int i = tid; i < NROWS; i += 256) {
      rix1[i] = 0;
      rix2[i] = 0;
    }
    __syncthreads();
    int c[16];
    int n1 = 0, n2 = 0;
#pragma unroll
    for (int j = 0; j < 16; j++) {
      const int t = targets[tid * 16 + j];
      c[j] = (t >= SP1) + (t >= SP2);
      n1 += (c[j] == 1);
      n2 += (c[j] == 2);
    }
    s1[tid] = n1;
    s2[tid] = n2;
    __syncthreads();
    for (int off = 1; off < 256; off <<= 1) {
      const int a1 = (tid >= off) ? s1[tid - off] : 0;
      const int a2 = (tid >= off) ? s2[tid - off] : 0;
      __syncthreads();
      s1[tid] += a1;
      s2[tid] += a2;
      __syncthreads();
    }
    int e1 = s1[tid] - n1, e2 = s2[tid] - n2;
#pragma unroll
    for (int j = 0; j < 16; j++) {
      const int row = tid * 16 + j;
      rixH[row] = row;
      if (c[j] == 1) {
        cidx[row] = e1;
        rix1[e1] = row;
        e1++;
      } else if (c[j] == 2) {
        cidx[row] = e2;
        rix2[e2] = row;
        e2++;
      } else {
        cidx[row] = 0;
      }
    }
    if (tid == 255) {
      counts[0] = s1[255];
      counts[1] = s2[255];
      counts[2] = NROWS;
    }
  }
}

#define MFMA_SC(a, b, c)                                                        \
  __builtin_amdgcn_mfma_scale_f32_16x16x128_f8f6f4((a), (b), (c), 0, 0, 0,      \
                                                   UNIT_SCALE, 0, UNIT_SCALE)

// one B-pair phase: read b[nb],b[nb+1]; barrier; lgkm; 8 MFMA; barrier.
// (all phases read slot t&1, staged before the tile began -> no intra-tile
// write hazard; the barriers align waves so read bursts of ready waves
// overlap MFMA clusters of lagging waves, T3/T5 regime)
#define PHASEB(nb)                                                              \
  {                                                                             \
    i32x4 l0 = *(const i32x4*)(sl + offB[nb]);                                  \
    i32x4 h0 = *(const i32x4*)(sl + offB[nb] + 16);                             \
    i32x4 l1 = *(const i32x4*)(sl + offB[(nb) + 1]);                            \
    i32x4 h1 = *(const i32x4*)(sl + offB[(nb) + 1] + 16);                       \
    i32x8 b0 = __builtin_shufflevector(l0, h0, 0, 1, 2, 3, 4, 5, 6, 7);         \
    i32x8 b1 = __builtin_shufflevector(l1, h1, 0, 1, 2, 3, 4, 5, 6, 7);         \
    __builtin_amdgcn_s_barrier();                                               \
    asm volatile("s_waitcnt lgkmcnt(0)" ::: "memory");                          \
    __builtin_amdgcn_sched_barrier(0);                                          \
    __builtin_amdgcn_s_setprio(1);                                              \
    _Pragma("unroll") for (int mi = 0; mi < 4; mi++) {                          \
      acc[mi][nb] = MFMA_SC(a8[mi], b0, acc[mi][nb]);                           \
      acc[mi][(nb) + 1] = MFMA_SC(a8[mi], b1, acc[mi][(nb) + 1]);               \
    }                                                                           \
    __builtin_amdgcn_s_setprio(0);                                              \
    __builtin_amdgcn_s_barrier();                                               \
  }

// ---- fused MX-fp8 GEMM (all 3 segments) + sum-exp epilogue ----
// r17 geometry (512 thr, 8 waves 4M x 2N, wave 64x128, BK=128, dbuf 147 KB,
// rix-indirect A staging) with the K-tile split into 4 PHASES (T3): each
// phase reads <=12 ds_read_b128 then runs an 8-MFMA cluster under setprio
// (T5) -- bounds the post-barrier LDS pile-up so staggered waves overlap
// LDS and matrix pipes (m218: phase-split+counted waits = +28-41%).
// Tile start gates the prefetched slot with {vmcnt(0); barrier}.
__global__ __launch_bounds__(512, 2) void gemm_fused(
    const unsigned char* __restrict__ Hf, const unsigned char* __restrict__ Wf,
    const float* __restrict__ biasr, float* __restrict__ ph,
    float* __restrict__ pt1, float* __restrict__ pt2,
    const int* __restrict__ counts, const int* __restrict__ rixH,
    const int* __restrict__ rix1, const int* __restrict__ rix2) {
  const int bid = blockIdx.x;
  const int* rix;
  float* partials;
  int CT, colbase, col_limit, b, Mc;
  if (bid < NB2) {
    b = bid; CT = CT_T2; colbase = CB_T2; col_limit = CL_T2;
    rix = rix2; partials = pt2; Mc = counts[1];
  } else if (bid < NB2 + NB1) {
    b = bid - NB2; CT = CT_T1; colbase = CB_T1; col_limit = CL_T1;
    rix = rix1; partials = pt1; Mc = counts[0];
  } else {
    b = bid - NB2 - NB1; CT = CT_HEAD; colbase = 0; col_limit = CL_HEAD;
    rix = rixH; partials = ph; Mc = NROWS;
  }
  const int rowTile = b / CT;
  const int colTile = b - rowTile * CT;
  if (rowTile * BM >= Mc) return;

  __shared__ __align__(16) unsigned char lds[2 * SLOT_B];  // 147456 B

  const int tid = threadIdx.x;
  const int w = tid >> 6, lane = tid & 63;
  const int wr = w >> 1, wc = w & 1;   // 4M x 2N
  const int fr = lane & 15, fq = lane >> 4;
  const unsigned char* Bg = Wf + (size_t)(colbase + colTile * BN) * HH;

  // staging: chunk c=i*512+tid (16B) -> dest byte c*16.
  // rows 0..255 = A (indirect via rix), 256..511 = B; 9 chunks/row
  // (j==8 dups j=0 into pad). A/B boundary at c=2304.
  const unsigned char* srcPtr[LPT];
#pragma unroll
  for (int i = 0; i < LPT; i++) {
    const int c = i * 512 + tid;
    const bool isA = c < NCH / 2;
    const int cc = isA ? c : c - NCH / 2;
    const int row = cc / 9;
    const int j = cc - row * 9;
    const int jb = (j < 8) ? j * 16 : 0;
    if (isA)
      srcPtr[i] = Hf + (size_t)rix[rowTile * BM + row] * HH + jb;
    else
      srcPtr[i] = Bg + (size_t)row * HH + jb;
  }

  // fragment read offsets (bytes within slot); hi half at +16 (contiguous)
  int offA[4], offB[8];
#pragma unroll
  for (int mi = 0; mi < 4; mi++) {
    const int R = wr * 64 + mi * 16 + fr;
    offA[mi] = R * ROWB + fq * 32;
  }
#pragma unroll
  for (int ni = 0; ni < 8; ni++) {
    const int R = wc * 128 + ni * 16 + fr;
    offB[ni] = A_SLOT_B + R * ROWB + fq * 32;
  }

  f32x4 acc[4][8];
#pragma unroll
  for (int i = 0; i < 4; i++)
#pragma unroll
    for (int j = 0; j < 8; j++) acc[i][j] = (f32x4){0.f, 0.f, 0.f, 0.f};

  auto STAGE = [&](int t) {
    unsigned char* base = lds + (t & 1) * SLOT_B;
    const int k0 = t * BK;
#pragma unroll
    for (int i = 0; i < LPT; i++)
      gload16(srcPtr[i] + k0, base + (i * 512 + tid) * 16);
  };

  STAGE(0);

#pragma unroll 1
  for (int t = 0; t < NKT; ++t) {
    // gate the slot staged for this tile (loads issued last tile's phase 0)
    asm volatile("s_waitcnt vmcnt(0)" ::: "memory");
    __builtin_amdgcn_s_barrier();

    const unsigned char* sl = lds + (t & 1) * SLOT_B;

    // ---- phase 0: A frags + B[0..1]; stage(t+1); MFMA ni=0,1 ----
    i32x8 a8[4];
#pragma unroll
    for (int mi = 0; mi < 4; mi++) {
      i32x4 lo = *(const i32x4*)(sl + offA[mi]);
      i32x4 hi = *(const i32x4*)(sl + offA[mi] + 16);
      a8[mi] = __builtin_shufflevector(lo, hi, 0, 1, 2, 3, 4, 5, 6, 7);
    }
    {
      i32x4 l0 = *(const i32x4*)(sl + offB[0]);
      i32x4 h0 = *(const i32x4*)(sl + offB[0] + 16);
      i32x4 l1 = *(const i32x4*)(sl + offB[1]);
      i32x4 h1 = *(const i32x4*)(sl + offB[1] + 16);
      i32x8 b0 = __builtin_shufflevector(l0, h0, 0, 1, 2, 3, 4, 5, 6, 7);
      i32x8 b1 = __builtin_shufflevector(l1, h1, 0, 1, 2, 3, 4, 5, 6, 7);
      if (t + 1 < NKT) STAGE(t + 1);
      __builtin_amdgcn_s_barrier();
      asm volatile("s_waitcnt lgkmcnt(0)" ::: "memory");
      __builtin_amdgcn_sched_barrier(0);
      __builtin_amdgcn_s_setprio(1);
#pragma unroll
      for (int mi = 0; mi < 4; mi++) {
        acc[mi][0] = MFMA_SC(a8[mi], b0, acc[mi][0]);
        acc[mi][1] = MFMA_SC(a8[mi], b1, acc[mi][1]);
      }
      __builtin_amdgcn_s_setprio(0);
      __builtin_amdgcn_s_barrier();
    }
    // ---- phases 1..3: B pairs 2/3, 4/5, 6/7 ----
    PHASEB(2);
    PHASEB(4);
    PHASEB(6);
  }

  // ---- epilogue: per-(row, 128-col wave chunk) sum of exp(logit/4096+bias) ----
  const int colw = colTile * BN + wc * 128;
  float biasv[8];
#pragma unroll
  for (int ni = 0; ni < 8; ni++) {
    const int gcol = colbase + colw + ni * 16 + fr;
    biasv[ni] = (gcol < col_limit) ? biasr[gcol] : -1e30f;
  }
  const int chunk = colTile * 2 + wc;
  const int pstride = CT * 2;

#pragma unroll
  for (int mi = 0; mi < 4; mi++) {
    const int rowg = rowTile * BM + wr * 64 + mi * 16 + fq * 4;
#pragma unroll
    for (int r = 0; r < 4; r++) {
      float p = 0.f;
#pragma unroll
      for (int ni = 0; ni < 8; ni++)
        p += __expf(acc[mi][ni][r] * INVSCALE + biasv[ni]);
#pragma unroll
      for (int m = 1; m < 16; m <<= 1) p += __shfl_xor(p, m);
      if (fr == 0) partials[(size_t)(rowg + r) * pstride + chunk] = p;
    }
  }
}

// ---- per-row: combine chunk partials, selected logits in fp32, loss ----
__global__ __launch_bounds__(256) void rowloss(
    const float* __restrict__ ph, const float* __restrict__ pt1,
    const float* __restrict__ pt2, const int* __restrict__ cidx,
    const float* __restrict__ hiddens, const float* __restrict__ weight,
    const float* __restrict__ bias, const float* __restrict__ tails,
    const float* __restrict__ tail_bias, const int* __restrict__ targets,
    float* __restrict__ losses) {
  const int row = blockIdx.x * 4 + (threadIdx.x >> 6);
  const int lane = threadIdx.x & 63;
  const int t = targets[row];
  const int cl = (t >= SP1) + (t >= SP2);

  float s0 = (lane < PH_STRIDE) ? ph[(size_t)row * PH_STRIDE + lane] : 0.f;
  float st = 0.f;
  if (cl == 1) {
    const float* P = pt1 + (size_t)cidx[row] * PT1_STRIDE;
    for (int c = lane; c < PT1_STRIDE; c += 64) st += P[c];
  } else if (cl == 2) {
    const float* P = pt2 + (size_t)cidx[row] * PT2_STRIDE;
    for (int c = lane; c < PT2_STRIDE; c += 64) st += P[c];
  }
#pragma unroll
  for (int m = 1; m < 64; m <<= 1) {
    s0 += __shfl_xor(s0, m);
    st += __shfl_xor(st, m);
  }

  const float* hv = hiddens + (size_t)row * HH;
  const float* w1;
  float b1;
  if (cl == 0) {
    w1 = weight + (size_t)t * HH;
    b1 = bias[t];
  } else if (cl == 1) {
    w1 = tails + HH;  // head col 4001 <-> tail_vectors[1]
    b1 = tail_bias[1];
  } else {
    w1 = tails;       // head col 4000 <-> tail_vectors[0]
    b1 = tail_bias[0];
  }
  float d1 = 0.f, d2 = 0.f;
  for (int i = lane; i < HH; i += 64) d1 += hv[i] * w1[i];
  if (cl > 0) {
    const float* w2 = weight + (size_t)t * HH;
    for (int i = lane; i < HH; i += 64) d2 += hv[i] * w2[i];
  }
#pragma unroll
  for (int m = 1; m < 64; m <<= 1) {
    d1 += __shfl_xor(d1, m);
    d2 += __shfl_xor(d2, m);
  }
  if (lane == 0) {
    float loss = logf(s0) - (d1 + b1);
    if (cl > 0) loss += logf(st) - (d2 + bias[t]);
    losses[row] = loss;
  }
}

__global__ void meanloss(const float* __restrict__ losses, float* __restrict__ out) {
  __shared__ float red[256];
  float s = 0.f;
  for (int i = threadIdx.x; i < NROWS; i += 256) s += losses[i];
  red[threadIdx.x] = s;
  __syncthreads();
  for (int st = 128; st > 0; st >>= 1) {
    if ((int)threadIdx.x < st) red[threadIdx.x] += red[threadIdx.x + st];
    __syncthreads();
  }
  if (threadIdx.x == 0) out[0] = red[0] / (float)NROWS;
}

extern "C" void kernel_launch(void* const* d_in, const int* in_sizes, int n_in,
                              void* d_out, int out_size, void* d_ws, size_t ws_size,
                              hipStream_t stream) {
  const float* weight = (const float*)d_in[0];
  const float* bias = (const float*)d_in[1];
  const float* hiddens = (const float*)d_in[2];
  const float* tails = (const float*)d_in[3];
  const float* tail_bias = (const float*)d_in[4];
  const int* targets = (const int*)d_in[5];
  float* out = (float*)d_out;

  char* ws = (char*)d_ws;
  unsigned char* Wf = (unsigned char*)ws;                      // 50432*1024 = 51,642,368
  unsigned char* Hf = (unsigned char*)(ws + 51642368);         //  4,194,304
  float* ph = (float*)(ws + 55836672);                         //  4096*32*4  =   524,288
  float* pt1 = (float*)(ws + 56360960);                        //  4096*126*4 = 2,064,384
  float* pt2 = (float*)(ws + 58425344);                        //  4096*236*4 = 3,866,624
  float* biasr = (float*)(ws + 62291968);                      //  50432*4    =   201,728
  int* cidx = (int*)(ws + 62493696);                           //  16,384
  int* counts = (int*)(ws + 62510080);                         //  64
  int* rixH = (int*)(ws + 62510144);                           //  16,384
  int* rix1 = (int*)(ws + 62526528);                           //  16,384
  int* rix2 = (int*)(ws + 62542912);                           //  16,384
  float* losses = (float*)(ws + 62559296);                     //  16,384

  hipLaunchKernelGGL(prep, dim3(PB_TOTAL), dim3(256), 0, stream, weight, tails, bias,
                     tail_bias, hiddens, targets, Wf, Hf, biasr, cidx, counts, rixH,
                     rix1, rix2);
  // fused: tail2 blocks [0,1888), tail1 [1888,2896), head [2896,3152)
  hipLaunchKernelGGL(gemm_fused, dim3(NB2 + NB1 + NBH), dim3(512), 0, stream, Hf, Wf,
                     biasr, ph, pt1, pt2, counts, rixH, rix1, rix2);
  hipLaunchKernelGGL(rowloss, dim3(NROWS / 4), dim3(256), 0, stream, ph, pt1, pt2, cidx,
                     hiddens, weight, bias, tails, tail_bias, targets, losses);
  hipLaunchKernelGGL(meanloss, dim3(1), dim3(256), 0, stream, losses, out);
}